// Round 4
// baseline (156.564 us; speedup 1.0000x reference)
//
#include <hip/hip_runtime.h>
#include <hip/hip_bf16.h>

// Q3 unpack: each int32 holds 10 x 3-bit fields at shifts 27,24,...,0.
// Output block k (k=0..9) along dim 0 is ((packed >> (27-3k)) & 7), int32.
// Streaming kernel: nontemporal loads/stores (bypass L2 allocate, 'nt' flag),
// 2 vectors per thread, every store instruction coalesced (lane i writes
// base + i*16B within each 4 KB chunk).

typedef int v4i __attribute__((ext_vector_type(4)));  // native vector: OK for nontemporal builtins

__global__ __launch_bounds__(256) void q3_unpack_kernel(
    const v4i* __restrict__ in, v4i* __restrict__ out, int nvec, int stride_vec) {
    const int tid = threadIdx.x;
    const int base = blockIdx.x * 512;  // 512 v4i per block, two 256-chunks

    const int i0 = base + tid;
    const int i1 = base + 256 + tid;

    v4i p0 = __builtin_nontemporal_load(&in[i0]);
    v4i p1 = __builtin_nontemporal_load(&in[i1]);

#pragma unroll
    for (int k = 0; k < 10; ++k) {
        const int sh = 27 - 3 * k;
        v4i v0 = (p0 >> sh) & 7;   // elementwise on ext_vector
        v4i v1 = (p1 >> sh) & 7;
        __builtin_nontemporal_store(v0, &out[(size_t)k * (size_t)stride_vec + (size_t)i0]);
        __builtin_nontemporal_store(v1, &out[(size_t)k * (size_t)stride_vec + (size_t)i1]);
    }
}

extern "C" void kernel_launch(void* const* d_in, const int* in_sizes, int n_in,
                              void* d_out, int out_size, void* d_ws, size_t ws_size,
                              hipStream_t stream) {
    const int* packed = (const int*)d_in[0];
    int* out = (int*)d_out;

    const int n_words = in_sizes[0];     // 4096*4096 = 16,777,216
    const int nvec = n_words / 4;        // 4,194,304 v4i
    const int stride_vec = n_words / 4;  // k-block stride in v4i units

    const int threads = 256;
    const int blocks = nvec / 512;       // 8192 blocks, exact fit

    q3_unpack_kernel<<<blocks, threads, 0, stream>>>(
        (const v4i*)packed, (v4i*)out, nvec, stride_vec);
}

// Round 5
// 153.911 us; speedup vs baseline: 1.0172x; 1.0172x over previous
//
#include <hip/hip_runtime.h>
#include <hip/hip_bf16.h>

// Q3 unpack: each int32 holds 10 x 3-bit fields at shifts 27,24,...,0.
// Output block k (k=0..9) along dim 0 is ((packed >> (27-3k)) & 7), int32.
//
// DRAM-locality-optimized streaming kernel: each block loads 2048 contiguous
// v4i (32 KB input) into registers (8 per thread), then writes each of the
// 10 output streams as one 32 KB contiguous burst (8 back-to-back coalesced
// 4 KB wave-stores). Long same-row DRAM bursts per channel instead of 512 B
// chunks alternating across 10 rows.

typedef int v4i __attribute__((ext_vector_type(4)));

constexpr int TPB = 256;
constexpr int VPT = 8;                 // v4i per thread
constexpr int VPB = TPB * VPT;         // 2048 v4i per block (32 KB)

__global__ __launch_bounds__(256) void q3_unpack_kernel(
    const v4i* __restrict__ in, v4i* __restrict__ out, int stride_vec) {
    const int tid = threadIdx.x;
    const size_t base = (size_t)blockIdx.x * VPB;

    v4i p[VPT];
#pragma unroll
    for (int j = 0; j < VPT; ++j)
        p[j] = __builtin_nontemporal_load(&in[base + (size_t)j * TPB + tid]);

#pragma unroll
    for (int k = 0; k < 10; ++k) {
        const int sh = 27 - 3 * k;
        const size_t ob = (size_t)k * (size_t)stride_vec + base + tid;
#pragma unroll
        for (int j = 0; j < VPT; ++j) {
            v4i v = (p[j] >> sh) & 7;
            __builtin_nontemporal_store(v, &out[ob + (size_t)j * TPB]);
        }
    }
}

extern "C" void kernel_launch(void* const* d_in, const int* in_sizes, int n_in,
                              void* d_out, int out_size, void* d_ws, size_t ws_size,
                              hipStream_t stream) {
    const int* packed = (const int*)d_in[0];
    int* out = (int*)d_out;

    const int n_words = in_sizes[0];     // 4096*4096 = 16,777,216
    const int nvec = n_words / 4;        // 4,194,304 v4i
    const int stride_vec = n_words / 4;  // k-block stride in v4i units

    const int blocks = nvec / VPB;       // 2048 blocks, exact fit

    q3_unpack_kernel<<<blocks, TPB, 0, stream>>>(
        (const v4i*)packed, (v4i*)out, stride_vec);
}

// Round 6
// 152.507 us; speedup vs baseline: 1.0266x; 1.0092x over previous
//
#include <hip/hip_runtime.h>
#include <hip/hip_bf16.h>

// Q3 unpack: each int32 holds 10 x 3-bit fields at shifts 27,24,...,0.
// Output block k (k=0..9) along dim 0 is ((packed >> (27-3k)) & 7), int32.
//
// Wave-contiguous streaming: each wave owns a contiguous 16 KB region per
// stream (64 lanes x 16 v4i). Its 16 coalesced 1 KB stores per k-stream are
// consecutive ascending addresses issued back-to-back -> long same-row DRAM
// runs per channel (vs 1 KB @ 4 KB stride in the previous layout).

typedef int v4i __attribute__((ext_vector_type(4)));

constexpr int TPB = 256;
constexpr int VPT = 16;                // v4i per thread
constexpr int VPB = TPB * VPT;         // 4096 v4i per block (64 KB)

__global__ __launch_bounds__(256) void q3_unpack_kernel(
    const v4i* __restrict__ in, v4i* __restrict__ out, int stride_vec) {
    const int lane = threadIdx.x & 63;
    const int w = threadIdx.x >> 6;
    // wave w owns v4i range [base + w*1024, base + w*1024 + 1024)
    const size_t wbase = (size_t)blockIdx.x * VPB + (size_t)w * (64 * VPT) + lane;

    v4i p[VPT];
#pragma unroll
    for (int j = 0; j < VPT; ++j)
        p[j] = __builtin_nontemporal_load(&in[wbase + (size_t)j * 64]);

#pragma unroll
    for (int k = 0; k < 10; ++k) {
        const int sh = 27 - 3 * k;
        const size_t ob = (size_t)k * (size_t)stride_vec + wbase;
#pragma unroll
        for (int j = 0; j < VPT; ++j) {
            v4i v = (p[j] >> sh) & 7;
            __builtin_nontemporal_store(v, &out[ob + (size_t)j * 64]);
        }
    }
}

extern "C" void kernel_launch(void* const* d_in, const int* in_sizes, int n_in,
                              void* d_out, int out_size, void* d_ws, size_t ws_size,
                              hipStream_t stream) {
    const int* packed = (const int*)d_in[0];
    int* out = (int*)d_out;

    const int n_words = in_sizes[0];     // 4096*4096 = 16,777,216
    const int nvec = n_words / 4;        // 4,194,304 v4i
    const int stride_vec = n_words / 4;  // k-block stride in v4i units

    const int blocks = nvec / VPB;       // 1024 blocks, exact fit

    q3_unpack_kernel<<<blocks, TPB, 0, stream>>>(
        (const v4i*)packed, (v4i*)out, stride_vec);
}